// Round 9
// baseline (131.007 us; speedup 1.0000x reference)
//
#include <hip/hip_runtime.h>

#define A_ 16
#define NA_ 8
#define DOBS_ 64

typedef _Float16 f16;
typedef f16 h2 __attribute__((ext_vector_type(2)));
typedef f16 v8h __attribute__((ext_vector_type(8)));
typedef float v4f __attribute__((ext_vector_type(4)));

__device__ __forceinline__ float fdot2f(h2 a, h2 b, float c) {
  return __builtin_amdgcn_fdot2(a, b, c, false);
}
__device__ __forceinline__ float lrelu(float x) { return x > 0.f ? x : 0.01f * x; }

struct P {
  const float *obs, *pol, *act;
  const float *kw1w, *kw1b, *kw2w, *kw2b, *qw1w, *qw1b, *qw2w, *qw2b;
  const float *ko1w, *ko1b, *ko2w, *ko2b, *qo1w, *qo1b, *qo2w, *qo2b;
  const float *av1w, *av1b, *av2w, *av2b, *fv1w, *fv1b, *fv2w, *fv2b;
  float *out0, *out1, *out2;
};

// ---------- dynamic-LDS memory map (f16 offsets) ----------
#define OBSH 0
#define OBSL 1152
#define X1Ho 2304
#define X1Lo 3456
#define X2Ho 4608
#define X2Lo 5760
#define EHO  6912
#define FLT  7168      // float region
#define F_PI   0
#define F_ACT  128
#define F_WSIG 256
#define F_WO   512
#define F_C0   768
#define F_S2   784
#define F_S3G  1872
#define F_WZK  2960
#define F_WZQ  3472
#define F_B    3984    // ko1b, ko2b, qo1b, qo2b (256 floats) -> region = 4240 floats
#define WKW1  15648
#define WQW1  20256
#define WKW2  24864
#define WQW2  29472
#define WKO1H 34080
#define WKO1L 38688
#define WKO2H 43296
#define WKO2L 47904
#define WQO1H 52512
#define WQO1L 57120
#define WQO2H 61728
#define WQO2L 66336    // ends 70944
// back overlays (liveness audited):
#define AV1H  15648    // over kw1/qw1 (dead after P1); staged P3
#define AV2H  21792    // over qw1 tail + kw2 head (dead after P2); staged P3
#define BACKB1 26400   // av1b/av2b, 128 floats; staged P3
#define SLA   26656    // slices 0..3 over kw2/qw2 (dead after P2); written in PAR
#define SLB   70944    // slices 4..7 (fresh)
#define AOSRC 77088
#define APTO  78240    // ends 79776
#define FV1H  34080    // over ko1 h/l (dead after PAR); staged P5
#define FV2PW 42784
#define BACKB2 43296   // fv1b/fv2b, 72 floats; staged P5 (over ko2h, dead after PAR)
#define LDS_F16 79776  // 159552 bytes

__device__ __forceinline__ v4f gemm_plain(const f16* Xh, const f16* W, float bv, int nt, int lane) {
  const int m = lane & 15, q = lane >> 4;
  v4f acc = {bv, bv, bv, bv};
  const v8h a0 = *(const v8h*)(Xh + m * 72 + q * 8);
  const v8h a1 = *(const v8h*)(Xh + m * 72 + 32 + q * 8);
  const f16* wr = W + (nt * 16 + m) * 72 + q * 8;
  acc = __builtin_amdgcn_mfma_f32_16x16x32_f16(a0, *(const v8h*)wr, acc, 0, 0, 0);
  acc = __builtin_amdgcn_mfma_f32_16x16x32_f16(a1, *(const v8h*)(wr + 32), acc, 0, 0, 0);
  return acc;
}

__device__ __forceinline__ v4f gemm_tile(const f16* Xh, const f16* Xl,
                                         const f16* Wh, const f16* Wl,
                                         float bv, int nt, int lane) {
  const int m = lane & 15, q = lane >> 4;
  v4f acc = {bv, bv, bv, bv};
  const v8h ah0 = *(const v8h*)(Xh + m * 72 + q * 8);
  const v8h ah1 = *(const v8h*)(Xh + m * 72 + 32 + q * 8);
  const v8h al0 = *(const v8h*)(Xl + m * 72 + q * 8);
  const v8h al1 = *(const v8h*)(Xl + m * 72 + 32 + q * 8);
  const f16* wr = Wh + (nt * 16 + m) * 72 + q * 8;
  const v8h bh0 = *(const v8h*)(wr);
  const v8h bh1 = *(const v8h*)(wr + 32);
  const f16* wr2 = Wl + (nt * 16 + m) * 72 + q * 8;
  const v8h bl0 = *(const v8h*)(wr2);
  const v8h bl1 = *(const v8h*)(wr2 + 32);
  acc = __builtin_amdgcn_mfma_f32_16x16x32_f16(ah0, bh0, acc, 0, 0, 0);
  acc = __builtin_amdgcn_mfma_f32_16x16x32_f16(ah1, bh1, acc, 0, 0, 0);
  acc = __builtin_amdgcn_mfma_f32_16x16x32_f16(ah0, bl0, acc, 0, 0, 0);
  acc = __builtin_amdgcn_mfma_f32_16x16x32_f16(ah1, bl1, acc, 0, 0, 0);
  acc = __builtin_amdgcn_mfma_f32_16x16x32_f16(al0, bh0, acc, 0, 0, 0);
  acc = __builtin_amdgcn_mfma_f32_16x16x32_f16(al1, bh1, acc, 0, 0, 0);
  return acc;
}

__device__ __forceinline__ void writeX(f16* Xh, f16* Xl, v4f acc, int nt, int lane, bool relu) {
  const int m = lane & 15, q = lane >> 4;
#pragma unroll
  for (int reg = 0; reg < 4; reg++) {
    float y = acc[reg];
    if (relu) y = lrelu(y);
    const f16 yh = (f16)y;
    Xh[(q * 4 + reg) * 72 + nt * 16 + m] = yh;
    Xl[(q * 4 + reg) * 72 + nt * 16 + m] = (f16)(y - (float)yh);
  }
}

__device__ __forceinline__ void putP(f16* W, float4 v, int o, int rq) {
  h2* d = (h2*)(W + o * 72 + 4 * rq);
  d[0] = h2{(f16)v.x, (f16)v.y};
  d[1] = h2{(f16)v.z, (f16)v.w};
}

__device__ __forceinline__ void putW(f16* Wh, f16* Wl, float4 v, int o, int rq) {
  h2* dh = (h2*)(Wh + o * 72 + 4 * rq);
  h2* dl = (h2*)(Wl + o * 72 + 4 * rq);
  const f16 hx = (f16)v.x, hy = (f16)v.y, hz = (f16)v.z, hw = (f16)v.w;
  dh[0] = h2{hx, hy};
  dh[1] = h2{hz, hw};
  dl[0] = h2{(f16)(v.x - (float)hx), (f16)(v.y - (float)hy)};
  dl[1] = h2{(f16)(v.z - (float)hz), (f16)(v.w - (float)hw)};
}

__device__ __forceinline__ v8h bfrag(const f16* Wm, int stride, int nt, int ks, int lane) {
  const int n = lane & 15, q = lane >> 4;
  return *(const v8h*)(Wm + (nt * 16 + n) * stride + ks * 32 + q * 8);
}

__device__ __forceinline__ void av_mlp2(const f16* obsh, const f16* av1H, const f16* av2H,
                                        const float* av1b, const float* av2b,
                                        f16* Hbuf, v8h az, int lane, v4f acc2[4]) {
  const int m = lane & 15, q = lane >> 4;
  const v8h a0 = *(const v8h*)(obsh + m * 72 + q * 8);
  const v8h a1 = *(const v8h*)(obsh + m * 72 + 32 + q * 8);
#pragma unroll
  for (int nt = 0; nt < 4; nt++) {
    const float bv = av1b[nt * 16 + m];
    v4f acc = {bv, bv, bv, bv};
    acc = __builtin_amdgcn_mfma_f32_16x16x32_f16(a0, bfrag(av1H, 96, nt, 0, lane), acc, 0, 0, 0);
    acc = __builtin_amdgcn_mfma_f32_16x16x32_f16(a1, bfrag(av1H, 96, nt, 1, lane), acc, 0, 0, 0);
    acc = __builtin_amdgcn_mfma_f32_16x16x32_f16(az, bfrag(av1H, 96, nt, 2, lane), acc, 0, 0, 0);
#pragma unroll
    for (int reg = 0; reg < 4; reg++)
      Hbuf[(q * 4 + reg) * 72 + nt * 16 + m] = (f16)lrelu(acc[reg]);
  }
  const v8h h0 = *(const v8h*)(Hbuf + m * 72 + q * 8);
  const v8h h1 = *(const v8h*)(Hbuf + m * 72 + 32 + q * 8);
#pragma unroll
  for (int nt = 0; nt < 4; nt++) {
    const float bv = av2b[nt * 16 + m];
    v4f acc = {bv, bv, bv, bv};
    acc = __builtin_amdgcn_mfma_f32_16x16x32_f16(h0, bfrag(av2H, 72, nt, 0, lane), acc, 0, 0, 0);
    acc = __builtin_amdgcn_mfma_f32_16x16x32_f16(h1, bfrag(av2H, 72, nt, 1, lane), acc, 0, 0, 0);
    acc2[nt] = acc;
  }
}

__global__ __launch_bounds__(512) void critic_fused(P p) {
  extern __shared__ f16 SMB[];
  float* F = (float*)(SMB + FLT);
  const int tid = threadIdx.x;
  const int b = blockIdx.x >> 1, ihalf = blockIdx.x & 1;
  const int w = tid >> 6, lane = tid & 63;
  const int m = lane & 15, quad = lane >> 4;
  const int o = tid & 63, r8 = tid >> 6;

  // ---- t0: issue ALL global loads once ----
  const float2 Robs = ((const float2*)(p.obs + (size_t)b * 1024))[tid];
  float Rpa = 0.f;
  if (tid < 128) Rpa = p.pol[(size_t)b * 128 + tid];
  else if (tid < 256) Rpa = p.act[(size_t)b * 128 + tid - 128];
  const float Rwzko = p.ko1w[(tid >> 3) * 72 + 64 + (tid & 7)];
  const float Rwzqo = p.qo1w[(tid >> 3) * 72 + 64 + (tid & 7)];
  float4 Rkw1[2], Rqw1[2], Rkw2[2], Rqw2[2], Rko1[2], Rko2[2], Rqo1[2], Rqo2[2];
#pragma unroll
  for (int h = 0; h < 2; h++) {
    const int rq = r8 + 8 * h;
    Rkw1[h] = *(const float4*)(p.kw1w + o * 64 + 4 * rq);
    Rqw1[h] = *(const float4*)(p.qw1w + o * 64 + 4 * rq);
    Rkw2[h] = *(const float4*)(p.kw2w + o * 64 + 4 * rq);
    Rqw2[h] = *(const float4*)(p.qw2w + o * 64 + 4 * rq);
    Rko1[h] = *(const float4*)(p.ko1w + o * 72 + 4 * rq);
    Rko2[h] = *(const float4*)(p.ko2w + o * 64 + 4 * rq);
    Rqo1[h] = *(const float4*)(p.qo1w + o * 72 + 4 * rq);
    Rqo2[h].x = p.qo2w[(4 * rq + 0) * 64 + o];
    Rqo2[h].y = p.qo2w[(4 * rq + 1) * 64 + o];
    Rqo2[h].z = p.qo2w[(4 * rq + 2) * 64 + o];
    Rqo2[h].w = p.qo2w[(4 * rq + 3) * 64 + o];
  }
  const int bi = (w & 3) * 16 + m;
  const float bias1 = (w < 4 ? p.kw1b : p.qw1b)[bi];
  const float bias2 = (w < 4 ? p.kw2b : p.qw2b)[bi];
  float rbo1 = 0.f, rbo2 = 0.f, rbo3 = 0.f, rbo4 = 0.f;
  if (tid < 64) { rbo1 = p.ko1b[tid]; rbo2 = p.ko2b[tid]; rbo3 = p.qo1b[tid]; rbo4 = p.qo2b[tid]; }
  const float4 rav1a = ((const float4*)p.av1w)[tid * 2];
  const float4 rav1b = ((const float4*)p.av1w)[tid * 2 + 1];
  const float rav1c = p.av1w[4096 + tid];
  const float4 rav2a = ((const float4*)p.av2w)[tid * 2];
  const float4 rav2b = ((const float4*)p.av2w)[tid * 2 + 1];
  float4 rfv[4];
#pragma unroll
  for (int qq = 0; qq < 4; qq++) rfv[qq] = ((const float4*)p.fv1w)[tid * 4 + qq];
  const float rfv2 = p.fv2w[tid];
  float rb1 = 0.f, rb2 = 0.f, rb3 = 0.f, rb4 = 0.f;
  if (tid < 64) { rb1 = p.av1b[tid]; rb2 = p.av2b[tid]; rb3 = p.fv1b[tid]; }
  if (tid < 8) rb4 = p.fv2b[tid];

  // ---- P0: stage inputs + ALL front weights ----
  {
    const int e0 = 2 * tid, r0 = e0 >> 6, c0i = e0 & 63;
    const f16 hx = (f16)Robs.x, hy = (f16)Robs.y;
    *(h2*)(SMB + OBSH + r0 * 72 + c0i) = h2{hx, hy};
    *(h2*)(SMB + OBSL + r0 * 72 + c0i) = h2{(f16)(Robs.x - (float)hx), (f16)(Robs.y - (float)hy)};
  }
  if (tid < 128) F[F_PI + tid] = Rpa;
  else if (tid < 256) F[F_ACT + tid - 128] = Rpa;
  F[F_WZK + tid] = Rwzko;
  { const int oo = tid >> 3, c = tid & 7; F[F_WZQ + (oo & 15) * 32 + (oo >> 4) * 8 + c] = Rwzqo; }
  if (tid < 64) {
    F[F_B + tid] = rbo1; F[F_B + 64 + tid] = rbo2;
    F[F_B + 128 + tid] = rbo3; F[F_B + 192 + tid] = rbo4;
  }
#pragma unroll
  for (int h = 0; h < 2; h++) {
    const int rq = r8 + 8 * h;
    putP(SMB + WKW1, Rkw1[h], o, rq);
    putP(SMB + WQW1, Rqw1[h], o, rq);
    putP(SMB + WKW2, Rkw2[h], o, rq);
    putP(SMB + WQW2, Rqw2[h], o, rq);
    putW(SMB + WKO1H, SMB + WKO1L, Rko1[h], o, rq);
    putW(SMB + WKO2H, SMB + WKO2L, Rko2[h], o, rq);
    putW(SMB + WQO1H, SMB + WQO1L, Rqo1[h], o, rq);
    putW(SMB + WQO2H, SMB + WQO2L, Rqo2[h], o, rq);
  }
  __syncthreads();

  // ---- P1: dual hidden ----
  {
    const f16* Wp = (w < 4) ? (SMB + WKW1) : (SMB + WQW1);
    f16* Xo = (w < 4) ? (SMB + X1Ho) : (SMB + X2Ho);
    v4f a = gemm_plain(SMB + OBSH, Wp, bias1, w & 3, lane);
#pragma unroll
    for (int reg = 0; reg < 4; reg++)
      Xo[(quad * 4 + reg) * 72 + (w & 3) * 16 + m] = (f16)lrelu(a[reg]);
  }
  __syncthreads();

  // ---- P2: key_z -> S2 (w0-3), query_z -> S3G (w4-7) ----
  {
    const f16* Wp = (w < 4) ? (SMB + WKW2) : (SMB + WQW2);
    const f16* Xi = (w < 4) ? (SMB + X1Ho) : (SMB + X2Ho);
    float* So = (w < 4) ? (F + F_S2) : (F + F_S3G);
    v4f a = gemm_plain(Xi, Wp, bias2, w & 3, lane);
#pragma unroll
    for (int reg = 0; reg < 4; reg++)
      So[(quad * 4 + reg) * 68 + (w & 3) * 16 + m] = a[reg];
  }
  __syncthreads();

  // ---- P3: score+sigmoid+out1 ; stage av weights (over dead kw/qw slots) ----
  {
    const int idx = tid >> 1, g2 = tid & 1;
    const int i = idx >> 4, j = idx & 15;
    float a0 = 0.f, a1 = 0.f, a2 = 0.f, a3 = 0.f;
#pragma unroll
    for (int t4 = 0; t4 < 8; t4++) {
      const float4 qv = *(const float4*)(F + F_S3G + i * 68 + g2 * 32 + 4 * t4);
      const float4 kv = *(const float4*)(F + F_S2 + j * 68 + g2 * 32 + 4 * t4);
      a0 += qv.x * kv.x; a1 += qv.y * kv.y; a2 += qv.z * kv.z; a3 += qv.w * kv.w;
    }
    float sc = (a0 + a1) + (a2 + a3);
    sc += __shfl_xor(sc, 1);
    if (g2 == 0) {
      const float wv = 1.f / (1.f + __expf(-sc * 0.125f));
      F[F_WSIG + idx] = wv;
      p.out1[(size_t)b * 256 + idx] = wv;
    }
  }
  {
    float av1v[8] = {rav1a.x, rav1a.y, rav1a.z, rav1a.w, rav1b.x, rav1b.y, rav1b.z, rav1b.w};
#pragma unroll
    for (int e = 0; e < 8; e++) {
      const int k = tid * 8 + e, rr = k / 72, cc = k - rr * 72;
      SMB[AV1H + rr * 96 + cc] = (f16)av1v[e];
    }
    const int k = 4096 + tid, rr = k / 72, cc = k - rr * 72;
    SMB[AV1H + rr * 96 + cc] = (f16)rav1c;
    const int row = tid >> 3, c0p = 72 + (tid & 7) * 3;
#pragma unroll
    for (int c = 0; c < 3; c++) SMB[AV1H + row * 96 + c0p + c] = (f16)0.f;
    float av2v[8] = {rav2a.x, rav2a.y, rav2a.z, rav2a.w, rav2b.x, rav2b.y, rav2b.z, rav2b.w};
#pragma unroll
    for (int e = 0; e < 8; e++) {
      const int k2 = tid * 8 + e;
      SMB[AV2H + (k2 >> 6) * 72 + (k2 & 63)] = (f16)av2v[e];
    }
    float* BF1 = (float*)(SMB + BACKB1);
    if (tid < 64) { BF1[tid] = rb1; BF1[64 + tid] = rb2; }
  }
  __syncthreads();

  // ================== PAR: ko-chain (w0) || Gqo (w1) || av bulk (w2-7) ==================
  const float* BF1 = (const float*)(SMB + BACKB1);
  if (w == 0) {
    // ko1-hid -> X2 (wave-local chain, no barriers needed)
#pragma unroll
    for (int nt = 0; nt < 4; nt++) {
      v4f a = gemm_tile(SMB + OBSH, SMB + OBSL, SMB + WKO1H, SMB + WKO1L, F[F_B + nt * 16 + m], nt, lane);
      const int oo = nt * 16 + m;
      float wzv[8];
      *(float4*)wzv = *(const float4*)(F + F_WZK + oo * 8);
      *(float4*)(wzv + 4) = *(const float4*)(F + F_WZK + oo * 8 + 4);
#pragma unroll
      for (int reg = 0; reg < 4; reg++) {
        const int rr = quad * 4 + reg;
        const float wrr = F[F_WSIG + rr * 17];
        float zp = 0.f;
#pragma unroll
        for (int c = 0; c < 8; c++) {
          const float zc = F[F_PI + rr * 8 + c] + wrr * (F[F_ACT + rr * 8 + c] - F[F_PI + rr * 8 + c]);
          zp += wzv[c] * zc;
        }
        const float y = lrelu(a[reg] + zp);
        const f16 yh = (f16)y;
        SMB[X2Ho + rr * 72 + oo] = yh;
        SMB[X2Lo + rr * 72 + oo] = (f16)(y - (float)yh);
      }
    }
    // key_o -> X1
#pragma unroll
    for (int nt = 0; nt < 4; nt++) {
      v4f a = gemm_tile(SMB + X2Ho, SMB + X2Lo, SMB + WKO2H, SMB + WKO2L, F[F_B + 64 + nt * 16 + m], nt, lane);
      writeX(SMB + X1Ho, SMB + X1Lo, a, nt, lane, false);
    }
    // ck -> S2
#pragma unroll
    for (int nt = 0; nt < 4; nt++) {
      v4f a = gemm_tile(SMB + X1Ho, SMB + X1Lo, SMB + WQO2H, SMB + WQO2L, 0.f, nt, lane);
#pragma unroll
      for (int reg = 0; reg < 4; reg++)
        F[F_S2 + (quad * 4 + reg) * 68 + nt * 16 + m] = a[reg];
    }
    // c0
    {
      const int r = lane >> 2, cs = (lane & 3) * 16;
      float t = 0.f;
#pragma unroll
      for (int c = 0; c < 16; c++) {
        const float kv = (float)SMB[X1Ho + r * 72 + cs + c] + (float)SMB[X1Lo + r * 72 + cs + c];
        t += kv * F[F_B + 192 + cs + c];
      }
      t += __shfl_xor(t, 1);
      t += __shfl_xor(t, 2);
      if ((lane & 3) == 0) F[F_C0 + r] = t;
    }
  } else if (w == 1) {
    // Gqo -> S3G
#pragma unroll
    for (int nt = 0; nt < 4; nt++) {
      v4f a = gemm_tile(SMB + OBSH, SMB + OBSL, SMB + WQO1H, SMB + WQO1L, F[F_B + 128 + nt * 16 + m], nt, lane);
#pragma unroll
      for (int reg = 0; reg < 4; reg++)
        F[F_S3G + m * 68 + (quad * 4 + reg) * 4 + nt] = a[reg];
    }
  } else {
    // av bulk: tasks 0..7 = AO slices (i = ihalf*8+t), 8 = AP, 9 = src
    auto do_task = [&](int t) {
      f16* Hb;
      v8h az = {};
      if (t < 8) {
        Hb = (t < 4) ? (SMB + SLA + t * 1536) : (SMB + SLB + (t - 4) * 1536);
        if (quad == 0) {
          const float wv = F[F_WSIG + (ihalf * 8 + t) * 16 + m];
#pragma unroll
          for (int c = 0; c < 8; c++)
            az[c] = (f16)(F[F_PI + m * 8 + c] + wv * (F[F_ACT + m * 8 + c] - F[F_PI + m * 8 + c]));
        }
      } else if (t == 8) {
        Hb = SMB + APTO;
        if (quad == 0) {
#pragma unroll
          for (int c = 0; c < 8; c++) az[c] = (f16)F[F_PI + m * 8 + c];
        }
      } else {
        Hb = SMB + AOSRC;
        if (quad == 0) {
          const float wv = F[F_WSIG + m * 17];
#pragma unroll
          for (int c = 0; c < 8; c++)
            az[c] = (f16)(F[F_PI + m * 8 + c] + wv * (F[F_ACT + m * 8 + c] - F[F_PI + m * 8 + c]));
        }
      }
      v4f acc2[4];
      av_mlp2(SMB + OBSH, SMB + AV1H, SMB + AV2H, BF1, BF1 + 64, Hb, az, lane, acc2);
      if (t < 9) {   // AOT / APT transposed layout
#pragma unroll
        for (int nt = 0; nt < 4; nt++)
#pragma unroll
          for (int reg = 0; reg < 4; reg++)
            Hb[(nt * 16 + m) * 24 + quad * 4 + reg] = (f16)acc2[nt][reg];
      } else {       // AOsrc row layout
#pragma unroll
        for (int nt = 0; nt < 4; nt++)
#pragma unroll
          for (int reg = 0; reg < 4; reg++)
            SMB[AOSRC + (quad * 4 + reg) * 72 + nt * 16 + m] = (f16)acc2[nt][reg];
      }
    };
    do_task(w - 2);
    if (w - 2 < 4) do_task(w - 2 + 6);
  }
  __syncthreads();

  // ---- P5: qo-score -> eh ; stage fv weights (over dead ko1/ko2 slots) ----
  {
    const int idx = tid >> 1, g2 = tid & 1;
    const int i = idx >> 4, j = idx & 15;
    const float wij = F[F_WSIG + i * 16 + j];
    float z[8];
#pragma unroll
    for (int c = 0; c < 8; c++)
      z[c] = F[F_PI + j * 8 + c] + wij * (F[F_ACT + j * 8 + c] - F[F_PI + j * 8 + c]);
    float sc = 0.f;
#pragma unroll
    for (int gg = 2 * g2; gg <= 2 * g2 + 1; gg++) {
#pragma unroll
      for (int t = 0; t < 16; t++) {
        const float4 wa = *(const float4*)(F + F_WZQ + t * 32 + gg * 8);
        const float4 wb = *(const float4*)(F + F_WZQ + t * 32 + gg * 8 + 4);
        float hv = F[F_S3G + t * 68 + j * 4 + gg]
          + wa.x * z[0] + wa.y * z[1] + wa.z * z[2] + wa.w * z[3]
          + wb.x * z[4] + wb.y * z[5] + wb.z * z[6] + wb.w * z[7];
        hv = lrelu(hv);
        sc += F[F_S2 + i * 68 + gg * 16 + t] * hv;
      }
    }
    sc += __shfl_xor(sc, 1);
    if (g2 == 0) {
      float yv = (sc + F[F_C0 + i]) * 0.125f;
      yv = fminf(fmaxf(yv, -5.f), 5.f);
      SMB[EHO + idx] = (f16)__expf(yv);
    }
  }
#pragma unroll
  for (int qq = 0; qq < 4; qq++) {
    const int e0 = tid * 16 + qq * 4;
    h2* d = (h2*)&SMB[FV1H + (e0 >> 7) * 136 + (e0 & 127)];
    d[0] = h2{(f16)rfv[qq].x, (f16)rfv[qq].y};
    d[1] = h2{(f16)rfv[qq].z, (f16)rfv[qq].w};
  }
  SMB[FV2PW + tid] = (f16)rfv2;
  {
    float* BF2 = (float*)(SMB + BACKB2);
    if (tid < 64) BF2[tid] = rb3;
    if (tid < 8) BF2[64 + tid] = rb4;
  }
  __syncthreads();

  // ---- P6: softmax -> wo ----
  if (tid < 256) {
    const int i = tid >> 4, j = tid & 15;
    float ev[16]; float mx = -1e30f;
#pragma unroll
    for (int jj = 0; jj < 16; jj++) { ev[jj] = (float)SMB[EHO + i * 16 + jj]; mx = fmaxf(mx, ev[jj]); }
    float den = 0.f;
#pragma unroll
    for (int jj = 0; jj < 16; jj++) den += __expf(ev[jj] - mx);
    F[F_WO + tid] = __expf(ev[j] - mx) / den;
  }
  __syncthreads();

  // ---- P7: final — mixed + fv1 + fv2 + out0 + out2 (all 8 waves) ----
  {
    const float* BF2 = (const float*)(SMB + BACKB2);
    const int i_ = ihalf * 8 + w;
    f16* Sl = (w < 4) ? (SMB + SLA + w * 1536) : (SMB + SLB + (w - 4) * 1536);
    // am from wo (folded AextH)
    v8h am;
#pragma unroll
    for (int e = 0; e < 8; e++) {
      const int j2 = quad * 8 + e;
      float v;
      if (j2 < 16) v = F[F_WO + m * 16 + j2] * 0.0625f;
      else v = (j2 - 16 == m) ? F[F_WO + m * 17] * 0.0625f : 0.f;
      am[e] = (f16)v;
    }
    {
      v4f macc[4];
#pragma unroll
      for (int nt = 0; nt < 4; nt++) {
        const int oo = nt * 16 + m;
        v8h bf;
        if (quad < 2) {
          bf = *(const v8h*)(Sl + oo * 24 + quad * 8);
        } else {
          const v8h apv = *(const v8h*)(&SMB[APTO + oo * 24 + (quad - 2) * 8]);
          const v8h aov = *(const v8h*)(Sl + oo * 24 + (quad - 2) * 8);
          bf = apv - aov;
        }
        v4f z4 = {0.f, 0.f, 0.f, 0.f};
        macc[nt] = __builtin_amdgcn_mfma_f32_16x16x32_f16(am, bf, z4, 0, 0, 0);
      }
#pragma unroll
      for (int nt = 0; nt < 4; nt++)
#pragma unroll
        for (int reg = 0; reg < 4; reg++)
          Sl[(quad * 4 + reg) * 72 + nt * 16 + m] = (f16)macc[nt][reg];
    }
    {
      const v8h f0 = *(const v8h*)(&SMB[AOSRC + m * 72 + quad * 8]);
      const v8h f1 = *(const v8h*)(&SMB[AOSRC + m * 72 + 32 + quad * 8]);
      const v8h f2 = *(const v8h*)(Sl + m * 72 + quad * 8);
      const v8h f3 = *(const v8h*)(Sl + m * 72 + 32 + quad * 8);
#pragma unroll
      for (int nt = 0; nt < 4; nt++) {
        const float bv = BF2[nt * 16 + m];
        v4f acc = {bv, bv, bv, bv};
        acc = __builtin_amdgcn_mfma_f32_16x16x32_f16(f0, bfrag(SMB + FV1H, 136, nt, 0, lane), acc, 0, 0, 0);
        acc = __builtin_amdgcn_mfma_f32_16x16x32_f16(f1, bfrag(SMB + FV1H, 136, nt, 1, lane), acc, 0, 0, 0);
        acc = __builtin_amdgcn_mfma_f32_16x16x32_f16(f2, bfrag(SMB + FV1H, 136, nt, 2, lane), acc, 0, 0, 0);
        acc = __builtin_amdgcn_mfma_f32_16x16x32_f16(f3, bfrag(SMB + FV1H, 136, nt, 3, lane), acc, 0, 0, 0);
#pragma unroll
        for (int reg = 0; reg < 4; reg++)
          Sl[(quad * 4 + reg) * 72 + nt * 16 + m] = (f16)lrelu(acc[reg]);
      }
    }
    {
      const int g2 = quad;
      float y0 = BF2[64 + 2 * g2], y1 = BF2[64 + 2 * g2 + 1];
#pragma unroll
      for (int o2 = 0; o2 < 32; o2++) {
        const h2 hh = *(const h2*)(Sl + m * 72 + 2 * o2);
        const h2 w0v = *(const h2*)(&SMB[FV2PW + (2 * g2) * 64 + 2 * o2]);
        const h2 w1v = *(const h2*)(&SMB[FV2PW + (2 * g2 + 1) * 64 + 2 * o2]);
        y0 = fdot2f(w0v, hh, y0);
        y1 = fdot2f(w1v, hh, y1);
      }
      *(float2*)(p.out0 + ((size_t)b * 256 + i_ * 16 + m) * 8 + 2 * g2) = make_float2(y0, y1);
    }
    // out2 rows for this i_
    {
      const float4 wv4 = *(const float4*)(F + F_WO + m * 16 + quad * 4);
      *(float4*)(p.out2 + ((size_t)b * 256 + i_ * 16 + m) * 16 + quad * 4) = wv4;
    }
  }
}

extern "C" void kernel_launch(void* const* d_in, const int* in_sizes, int n_in,
                              void* d_out, int out_size, void* d_ws, size_t ws_size,
                              hipStream_t stream) {
  P p;
  p.obs = (const float*)d_in[0];
  p.pol = (const float*)d_in[1];
  p.act = (const float*)d_in[2];
  p.kw1w = (const float*)d_in[3];  p.kw1b = (const float*)d_in[4];
  p.kw2w = (const float*)d_in[5];  p.kw2b = (const float*)d_in[6];
  p.qw1w = (const float*)d_in[7];  p.qw1b = (const float*)d_in[8];
  p.qw2w = (const float*)d_in[9];  p.qw2b = (const float*)d_in[10];
  p.ko1w = (const float*)d_in[11]; p.ko1b = (const float*)d_in[12];
  p.ko2w = (const float*)d_in[13]; p.ko2b = (const float*)d_in[14];
  p.qo1w = (const float*)d_in[15]; p.qo1b = (const float*)d_in[16];
  p.qo2w = (const float*)d_in[17]; p.qo2b = (const float*)d_in[18];
  p.av1w = (const float*)d_in[19]; p.av1b = (const float*)d_in[20];
  p.av2w = (const float*)d_in[21]; p.av2b = (const float*)d_in[22];
  p.fv1w = (const float*)d_in[23]; p.fv1b = (const float*)d_in[24];
  p.fv2w = (const float*)d_in[25]; p.fv2b = (const float*)d_in[26];

  const int Bn = in_sizes[0] / (A_ * DOBS_);   // 128
  p.out0 = (float*)d_out;
  p.out1 = p.out0 + (size_t)Bn * A_ * A_ * NA_;
  p.out2 = p.out1 + (size_t)Bn * A_ * A_;

  const size_t lds_bytes = (size_t)LDS_F16 * sizeof(f16);   // 159552
  (void)hipFuncSetAttribute(reinterpret_cast<const void*>(critic_fused),
                            hipFuncAttributeMaxDynamicSharedMemorySize, (int)lds_bytes);
  hipLaunchKernelGGL(critic_fused, dim3(2 * Bn), dim3(512), lds_bytes, stream, p);
}

// Round 10
// 125.819 us; speedup vs baseline: 1.0412x; 1.0412x over previous
//
#include <hip/hip_runtime.h>

#define A_ 16
#define NA_ 8
#define DOBS_ 64

typedef _Float16 f16;
typedef f16 h2 __attribute__((ext_vector_type(2)));
typedef f16 v8h __attribute__((ext_vector_type(8)));
typedef float v4f __attribute__((ext_vector_type(4)));

__device__ __forceinline__ float fdot2f(h2 a, h2 b, float c) {
  return __builtin_amdgcn_fdot2(a, b, c, false);
}
__device__ __forceinline__ float lrelu(float x) { return x > 0.f ? x : 0.01f * x; }

struct P {
  const float *obs, *pol, *act;
  const float *kw1w, *kw1b, *kw2w, *kw2b, *qw1w, *qw1b, *qw2w, *qw2b;
  const float *ko1w, *ko1b, *ko2w, *ko2b, *qo1w, *qo1b, *qo2w, *qo2b;
  const float *av1w, *av1b, *av2w, *av2b, *fv1w, *fv1b, *fv2w, *fv2b;
  float *out0, *out1, *out2;
};

// ---------- dynamic-LDS memory map (f16 offsets) ----------
#define OBSH 0
#define OBSL 1152
#define X1Ho 2304
#define X1Lo 3456
#define X2Ho 4608
#define X2Lo 5760
#define EHO  6912
#define FLT  7168      // float region
#define F_PI   0
#define F_ACT  128
#define F_WSIG 256
#define F_WO   512
#define F_C0   768
#define F_S2   784
#define F_S3G  1872
#define F_WZK  2960
#define F_WZQ  3472
#define F_B    3984    // ko1b, ko2b, qo1b, qo2b (256 floats)
#define WKW1  15648
#define WQW1  20256
#define WKW2  24864
#define WQW2  29472
#define WKO1H 34080
#define WKO1L 38688
#define WKO2H 43296
#define WKO2L 47904
#define WQO1H 52512
#define WQO1L 57120
#define WQO2H 61728
#define WQO2L 66336    // ends 70944
// back overlays (liveness audited):
#define AV1H  15648    // over kw1/qw1 (dead after P1); staged P3
#define AV2H  21792    // over qw1 tail / kw2 head (dead after P2); staged P3
#define BACKB1 26400   // av1b/av2b (128 floats); staged P3
#define SLA   26656    // AO slices 0-3, over kw2/qw2 tails (dead after P2); written P4
#define SLB   70944    // AO slices 4-7 (fresh); written P5
#define AOSRC 77088    // attn_src rows (16x72); written P5
#define APTO  78240    // AP^T (64x24); written P5 ; ends 79776
#define FV1H  34080    // over ko1 h/l (dead after P4); staged P8
#define FV2PW 42784    // tail of ko1l; staged P8
#define BACKB2 43296   // over ko2h (dead after P5); 72 floats; staged P8
#define LDS_F16 79776  // 159552 bytes

__device__ __forceinline__ v4f gemm_plain(const f16* Xh, const f16* W, float bv, int nt, int lane) {
  const int m = lane & 15, q = lane >> 4;
  v4f acc = {bv, bv, bv, bv};
  const v8h a0 = *(const v8h*)(Xh + m * 72 + q * 8);
  const v8h a1 = *(const v8h*)(Xh + m * 72 + 32 + q * 8);
  const f16* wr = W + (nt * 16 + m) * 72 + q * 8;
  acc = __builtin_amdgcn_mfma_f32_16x16x32_f16(a0, *(const v8h*)wr, acc, 0, 0, 0);
  acc = __builtin_amdgcn_mfma_f32_16x16x32_f16(a1, *(const v8h*)(wr + 32), acc, 0, 0, 0);
  return acc;
}

__device__ __forceinline__ v4f gemm_tile(const f16* Xh, const f16* Xl,
                                         const f16* Wh, const f16* Wl,
                                         float bv, int nt, int lane) {
  const int m = lane & 15, q = lane >> 4;
  v4f acc = {bv, bv, bv, bv};
  const v8h ah0 = *(const v8h*)(Xh + m * 72 + q * 8);
  const v8h ah1 = *(const v8h*)(Xh + m * 72 + 32 + q * 8);
  const v8h al0 = *(const v8h*)(Xl + m * 72 + q * 8);
  const v8h al1 = *(const v8h*)(Xl + m * 72 + 32 + q * 8);
  const f16* wr = Wh + (nt * 16 + m) * 72 + q * 8;
  const v8h bh0 = *(const v8h*)(wr);
  const v8h bh1 = *(const v8h*)(wr + 32);
  const f16* wr2 = Wl + (nt * 16 + m) * 72 + q * 8;
  const v8h bl0 = *(const v8h*)(wr2);
  const v8h bl1 = *(const v8h*)(wr2 + 32);
  acc = __builtin_amdgcn_mfma_f32_16x16x32_f16(ah0, bh0, acc, 0, 0, 0);
  acc = __builtin_amdgcn_mfma_f32_16x16x32_f16(ah1, bh1, acc, 0, 0, 0);
  acc = __builtin_amdgcn_mfma_f32_16x16x32_f16(ah0, bl0, acc, 0, 0, 0);
  acc = __builtin_amdgcn_mfma_f32_16x16x32_f16(ah1, bl1, acc, 0, 0, 0);
  acc = __builtin_amdgcn_mfma_f32_16x16x32_f16(al0, bh0, acc, 0, 0, 0);
  acc = __builtin_amdgcn_mfma_f32_16x16x32_f16(al1, bh1, acc, 0, 0, 0);
  return acc;
}

__device__ __forceinline__ void writeX(f16* Xh, f16* Xl, v4f acc, int nt, int lane, bool relu) {
  const int m = lane & 15, q = lane >> 4;
#pragma unroll
  for (int reg = 0; reg < 4; reg++) {
    float y = acc[reg];
    if (relu) y = lrelu(y);
    const f16 yh = (f16)y;
    Xh[(q * 4 + reg) * 72 + nt * 16 + m] = yh;
    Xl[(q * 4 + reg) * 72 + nt * 16 + m] = (f16)(y - (float)yh);
  }
}

__device__ __forceinline__ void putP(f16* W, float4 v, int o, int rq) {
  h2* d = (h2*)(W + o * 72 + 4 * rq);
  d[0] = h2{(f16)v.x, (f16)v.y};
  d[1] = h2{(f16)v.z, (f16)v.w};
}

__device__ __forceinline__ void putW(f16* Wh, f16* Wl, float4 v, int o, int rq) {
  h2* dh = (h2*)(Wh + o * 72 + 4 * rq);
  h2* dl = (h2*)(Wl + o * 72 + 4 * rq);
  const f16 hx = (f16)v.x, hy = (f16)v.y, hz = (f16)v.z, hw = (f16)v.w;
  dh[0] = h2{hx, hy};
  dh[1] = h2{hz, hw};
  dl[0] = h2{(f16)(v.x - (float)hx), (f16)(v.y - (float)hy)};
  dl[1] = h2{(f16)(v.z - (float)hz), (f16)(v.w - (float)hw)};
}

__device__ __forceinline__ v8h bfrag(const f16* Wm, int stride, int nt, int ks, int lane) {
  const int n = lane & 15, q = lane >> 4;
  return *(const v8h*)(Wm + (nt * 16 + n) * stride + ks * 32 + q * 8);
}

__device__ __forceinline__ void av_mlp2(const f16* obsh, const f16* av1H, const f16* av2H,
                                        const float* av1b, const float* av2b,
                                        f16* Hbuf, v8h az, int lane, v4f acc2[4]) {
  const int m = lane & 15, q = lane >> 4;
  const v8h a0 = *(const v8h*)(obsh + m * 72 + q * 8);
  const v8h a1 = *(const v8h*)(obsh + m * 72 + 32 + q * 8);
#pragma unroll
  for (int nt = 0; nt < 4; nt++) {
    const float bv = av1b[nt * 16 + m];
    v4f acc = {bv, bv, bv, bv};
    acc = __builtin_amdgcn_mfma_f32_16x16x32_f16(a0, bfrag(av1H, 96, nt, 0, lane), acc, 0, 0, 0);
    acc = __builtin_amdgcn_mfma_f32_16x16x32_f16(a1, bfrag(av1H, 96, nt, 1, lane), acc, 0, 0, 0);
    acc = __builtin_amdgcn_mfma_f32_16x16x32_f16(az, bfrag(av1H, 96, nt, 2, lane), acc, 0, 0, 0);
#pragma unroll
    for (int reg = 0; reg < 4; reg++)
      Hbuf[(q * 4 + reg) * 72 + nt * 16 + m] = (f16)lrelu(acc[reg]);
  }
  const v8h h0 = *(const v8h*)(Hbuf + m * 72 + q * 8);
  const v8h h1 = *(const v8h*)(Hbuf + m * 72 + 32 + q * 8);
#pragma unroll
  for (int nt = 0; nt < 4; nt++) {
    const float bv = av2b[nt * 16 + m];
    v4f acc = {bv, bv, bv, bv};
    acc = __builtin_amdgcn_mfma_f32_16x16x32_f16(h0, bfrag(av2H, 72, nt, 0, lane), acc, 0, 0, 0);
    acc = __builtin_amdgcn_mfma_f32_16x16x32_f16(h1, bfrag(av2H, 72, nt, 1, lane), acc, 0, 0, 0);
    acc2[nt] = acc;
  }
}

__global__ __launch_bounds__(512) void critic_fused(P p) {
  extern __shared__ f16 SMB[];
  float* F = (float*)(SMB + FLT);
  const int tid = threadIdx.x;
  const int b = blockIdx.x >> 1, ihalf = blockIdx.x & 1;
  const int w = tid >> 6, lane = tid & 63;
  const int m = lane & 15, quad = lane >> 4;
  const int o = tid & 63, r8 = tid >> 6;

  // ---- t0: issue ALL global loads once ----
  const float2 Robs = ((const float2*)(p.obs + (size_t)b * 1024))[tid];
  float Rpa = 0.f;
  if (tid < 128) Rpa = p.pol[(size_t)b * 128 + tid];
  else if (tid < 256) Rpa = p.act[(size_t)b * 128 + tid - 128];
  const float Rwzko = p.ko1w[(tid >> 3) * 72 + 64 + (tid & 7)];
  const float Rwzqo = p.qo1w[(tid >> 3) * 72 + 64 + (tid & 7)];
  float4 Rkw1[2], Rqw1[2], Rkw2[2], Rqw2[2], Rko1[2], Rko2[2], Rqo1[2], Rqo2[2];
#pragma unroll
  for (int h = 0; h < 2; h++) {
    const int rq = r8 + 8 * h;
    Rkw1[h] = *(const float4*)(p.kw1w + o * 64 + 4 * rq);
    Rqw1[h] = *(const float4*)(p.qw1w + o * 64 + 4 * rq);
    Rkw2[h] = *(const float4*)(p.kw2w + o * 64 + 4 * rq);
    Rqw2[h] = *(const float4*)(p.qw2w + o * 64 + 4 * rq);
    Rko1[h] = *(const float4*)(p.ko1w + o * 72 + 4 * rq);
    Rko2[h] = *(const float4*)(p.ko2w + o * 64 + 4 * rq);
    Rqo1[h] = *(const float4*)(p.qo1w + o * 72 + 4 * rq);
    Rqo2[h].x = p.qo2w[(4 * rq + 0) * 64 + o];
    Rqo2[h].y = p.qo2w[(4 * rq + 1) * 64 + o];
    Rqo2[h].z = p.qo2w[(4 * rq + 2) * 64 + o];
    Rqo2[h].w = p.qo2w[(4 * rq + 3) * 64 + o];
  }
  const int bi = (w & 3) * 16 + m;
  const float bias1 = (w < 4 ? p.kw1b : p.qw1b)[bi];
  const float bias2 = (w < 4 ? p.kw2b : p.qw2b)[bi];
  float rbo1 = 0.f, rbo2 = 0.f, rbo3 = 0.f, rbo4 = 0.f;
  if (tid < 64) { rbo1 = p.ko1b[tid]; rbo2 = p.ko2b[tid]; rbo3 = p.qo1b[tid]; rbo4 = p.qo2b[tid]; }
  const float4 rav1a = ((const float4*)p.av1w)[tid * 2];
  const float4 rav1b = ((const float4*)p.av1w)[tid * 2 + 1];
  const float rav1c = p.av1w[4096 + tid];
  const float4 rav2a = ((const float4*)p.av2w)[tid * 2];
  const float4 rav2b = ((const float4*)p.av2w)[tid * 2 + 1];
  float4 rfv[4];
#pragma unroll
  for (int qq = 0; qq < 4; qq++) rfv[qq] = ((const float4*)p.fv1w)[tid * 4 + qq];
  const float rfv2 = p.fv2w[tid];
  float rb1 = 0.f, rb2 = 0.f, rb3 = 0.f, rb4 = 0.f;
  if (tid < 64) { rb1 = p.av1b[tid]; rb2 = p.av2b[tid]; rb3 = p.fv1b[tid]; }
  if (tid < 8) rb4 = p.fv2b[tid];

  // ---- P0: stage inputs + ALL front weights ----
  {
    const int e0 = 2 * tid, r0 = e0 >> 6, c0i = e0 & 63;
    const f16 hx = (f16)Robs.x, hy = (f16)Robs.y;
    *(h2*)(SMB + OBSH + r0 * 72 + c0i) = h2{hx, hy};
    *(h2*)(SMB + OBSL + r0 * 72 + c0i) = h2{(f16)(Robs.x - (float)hx), (f16)(Robs.y - (float)hy)};
  }
  if (tid < 128) F[F_PI + tid] = Rpa;
  else if (tid < 256) F[F_ACT + tid - 128] = Rpa;
  F[F_WZK + tid] = Rwzko;
  { const int oo = tid >> 3, c = tid & 7; F[F_WZQ + (oo & 15) * 32 + (oo >> 4) * 8 + c] = Rwzqo; }
  if (tid < 64) {
    F[F_B + tid] = rbo1; F[F_B + 64 + tid] = rbo2;
    F[F_B + 128 + tid] = rbo3; F[F_B + 192 + tid] = rbo4;
  }
#pragma unroll
  for (int h = 0; h < 2; h++) {
    const int rq = r8 + 8 * h;
    putP(SMB + WKW1, Rkw1[h], o, rq);
    putP(SMB + WQW1, Rqw1[h], o, rq);
    putP(SMB + WKW2, Rkw2[h], o, rq);
    putP(SMB + WQW2, Rqw2[h], o, rq);
    putW(SMB + WKO1H, SMB + WKO1L, Rko1[h], o, rq);
    putW(SMB + WKO2H, SMB + WKO2L, Rko2[h], o, rq);
    putW(SMB + WQO1H, SMB + WQO1L, Rqo1[h], o, rq);
    putW(SMB + WQO2H, SMB + WQO2L, Rqo2[h], o, rq);
  }
  __syncthreads();

  // ---- P1: dual hidden ----
  {
    const f16* Wp = (w < 4) ? (SMB + WKW1) : (SMB + WQW1);
    f16* Xo = (w < 4) ? (SMB + X1Ho) : (SMB + X2Ho);
    v4f a = gemm_plain(SMB + OBSH, Wp, bias1, w & 3, lane);
#pragma unroll
    for (int reg = 0; reg < 4; reg++)
      Xo[(quad * 4 + reg) * 72 + (w & 3) * 16 + m] = (f16)lrelu(a[reg]);
  }
  __syncthreads();

  // ---- P2: key_z -> S2 (w0-3), query_z -> S3G (w4-7) ----
  {
    const f16* Wp = (w < 4) ? (SMB + WKW2) : (SMB + WQW2);
    const f16* Xi = (w < 4) ? (SMB + X1Ho) : (SMB + X2Ho);
    float* So = (w < 4) ? (F + F_S2) : (F + F_S3G);
    v4f a = gemm_plain(Xi, Wp, bias2, w & 3, lane);
#pragma unroll
    for (int reg = 0; reg < 4; reg++)
      So[(quad * 4 + reg) * 68 + (w & 3) * 16 + m] = a[reg];
  }
  __syncthreads();

  // ---- P3: score+sigmoid+out1 ; stage av weights (over dead kw/qw slots) ----
  {
    const int idx = tid >> 1, g2 = tid & 1;
    const int i = idx >> 4, j = idx & 15;
    float a0 = 0.f, a1 = 0.f, a2 = 0.f, a3 = 0.f;
#pragma unroll
    for (int t4 = 0; t4 < 8; t4++) {
      const float4 qv = *(const float4*)(F + F_S3G + i * 68 + g2 * 32 + 4 * t4);
      const float4 kv = *(const float4*)(F + F_S2 + j * 68 + g2 * 32 + 4 * t4);
      a0 += qv.x * kv.x; a1 += qv.y * kv.y; a2 += qv.z * kv.z; a3 += qv.w * kv.w;
    }
    float sc = (a0 + a1) + (a2 + a3);
    sc += __shfl_xor(sc, 1);
    if (g2 == 0) {
      const float wv = 1.f / (1.f + __expf(-sc * 0.125f));
      F[F_WSIG + idx] = wv;
      p.out1[(size_t)b * 256 + idx] = wv;
    }
  }
  {
    float av1v[8] = {rav1a.x, rav1a.y, rav1a.z, rav1a.w, rav1b.x, rav1b.y, rav1b.z, rav1b.w};
#pragma unroll
    for (int e = 0; e < 8; e++) {
      const int k = tid * 8 + e, rr = k / 72, cc = k - rr * 72;
      SMB[AV1H + rr * 96 + cc] = (f16)av1v[e];
    }
    const int k = 4096 + tid, rr = k / 72, cc = k - rr * 72;
    SMB[AV1H + rr * 96 + cc] = (f16)rav1c;
    const int row = tid >> 3, c0p = 72 + (tid & 7) * 3;
#pragma unroll
    for (int c = 0; c < 3; c++) SMB[AV1H + row * 96 + c0p + c] = (f16)0.f;
    float av2v[8] = {rav2a.x, rav2a.y, rav2a.z, rav2a.w, rav2b.x, rav2b.y, rav2b.z, rav2b.w};
#pragma unroll
    for (int e = 0; e < 8; e++) {
      const int k2 = tid * 8 + e;
      SMB[AV2H + (k2 >> 6) * 72 + (k2 & 63)] = (f16)av2v[e];
    }
    float* BF1w = (float*)(SMB + BACKB1);
    if (tid < 64) { BF1w[tid] = rb1; BF1w[64 + tid] = rb2; }
  }
  __syncthreads();

  const float* BF1 = (const float*)(SMB + BACKB1);
  // av task helper: t in 0..7 = AO slice t (i = ihalf*8+t); 8 = AP; 9 = src
  auto do_av_task = [&](int t) {
    f16* Hb;
    v8h az = {};
    if (t < 8) {
      Hb = (t < 4) ? (SMB + SLA + t * 1536) : (SMB + SLB + (t - 4) * 1536);
      if (quad == 0) {
        const float wv = F[F_WSIG + (ihalf * 8 + t) * 16 + m];
#pragma unroll
        for (int c = 0; c < 8; c++)
          az[c] = (f16)(F[F_PI + m * 8 + c] + wv * (F[F_ACT + m * 8 + c] - F[F_PI + m * 8 + c]));
      }
    } else if (t == 8) {
      Hb = SMB + APTO;
      if (quad == 0) {
#pragma unroll
        for (int c = 0; c < 8; c++) az[c] = (f16)F[F_PI + m * 8 + c];
      }
    } else {
      Hb = SMB + AOSRC;
      if (quad == 0) {
        const float wv = F[F_WSIG + m * 17];
#pragma unroll
        for (int c = 0; c < 8; c++)
          az[c] = (f16)(F[F_PI + m * 8 + c] + wv * (F[F_ACT + m * 8 + c] - F[F_PI + m * 8 + c]));
      }
    }
    v4f acc2[4];
    av_mlp2(SMB + OBSH, SMB + AV1H, SMB + AV2H, BF1, BF1 + 64, Hb, az, lane, acc2);
    if (t < 9) {   // AOT / APT transposed layout [o][r]
#pragma unroll
      for (int nt = 0; nt < 4; nt++)
#pragma unroll
        for (int reg = 0; reg < 4; reg++)
          Hb[(nt * 16 + m) * 24 + quad * 4 + reg] = (f16)acc2[nt][reg];
    } else {       // src row layout [k][o]
#pragma unroll
      for (int nt = 0; nt < 4; nt++)
#pragma unroll
        for (int reg = 0; reg < 4; reg++)
          SMB[AOSRC + (quad * 4 + reg) * 72 + nt * 16 + m] = (f16)acc2[nt][reg];
    }
  };

  // ---- P4: w0-1 ko1-hid (2 tiles each) | w2-3 Gqo | w4-7 AO0-3 ----
  if (w < 2) {
#pragma unroll
    for (int k2 = 0; k2 < 2; k2++) {
      const int nt = w * 2 + k2;
      v4f a = gemm_tile(SMB + OBSH, SMB + OBSL, SMB + WKO1H, SMB + WKO1L, F[F_B + nt * 16 + m], nt, lane);
      const int oo = nt * 16 + m;
      float wzv[8];
      *(float4*)wzv = *(const float4*)(F + F_WZK + oo * 8);
      *(float4*)(wzv + 4) = *(const float4*)(F + F_WZK + oo * 8 + 4);
#pragma unroll
      for (int reg = 0; reg < 4; reg++) {
        const int rr = quad * 4 + reg;
        const float wrr = F[F_WSIG + rr * 17];
        float zp = 0.f;
#pragma unroll
        for (int c = 0; c < 8; c++) {
          const float zc = F[F_PI + rr * 8 + c] + wrr * (F[F_ACT + rr * 8 + c] - F[F_PI + rr * 8 + c]);
          zp += wzv[c] * zc;
        }
        const float y = lrelu(a[reg] + zp);
        const f16 yh = (f16)y;
        SMB[X2Ho + rr * 72 + oo] = yh;
        SMB[X2Lo + rr * 72 + oo] = (f16)(y - (float)yh);
      }
    }
  } else if (w < 4) {
#pragma unroll
    for (int k2 = 0; k2 < 2; k2++) {
      const int nt = (w - 2) * 2 + k2;
      v4f a = gemm_tile(SMB + OBSH, SMB + OBSL, SMB + WQO1H, SMB + WQO1L, F[F_B + 128 + nt * 16 + m], nt, lane);
#pragma unroll
      for (int reg = 0; reg < 4; reg++)
        F[F_S3G + m * 68 + (quad * 4 + reg) * 4 + nt] = a[reg];
    }
  } else {
    do_av_task(w - 4);   // AO0-3
  }
  __syncthreads();

  // ---- P5: w0-1 key_o | w2 AP | w3 src | w4-7 AO4-7 ----
  if (w < 2) {
#pragma unroll
    for (int k2 = 0; k2 < 2; k2++) {
      const int nt = w * 2 + k2;
      v4f a = gemm_tile(SMB + X2Ho, SMB + X2Lo, SMB + WKO2H, SMB + WKO2L, F[F_B + 64 + nt * 16 + m], nt, lane);
      writeX(SMB + X1Ho, SMB + X1Lo, a, nt, lane, false);
    }
  } else if (w == 2) {
    do_av_task(8);
  } else if (w == 3) {
    do_av_task(9);
  } else {
    do_av_task(w);       // AO4-7
  }
  __syncthreads();

  // ---- P6: w0-1 ck + c0 ----
  if (w < 2) {
#pragma unroll
    for (int k2 = 0; k2 < 2; k2++) {
      const int nt = w * 2 + k2;
      v4f a = gemm_tile(SMB + X1Ho, SMB + X1Lo, SMB + WQO2H, SMB + WQO2L, 0.f, nt, lane);
#pragma unroll
      for (int reg = 0; reg < 4; reg++)
        F[F_S2 + (quad * 4 + reg) * 68 + nt * 16 + m] = a[reg];
    }
    {
      const int rr = tid >> 3, cs = (tid & 7) * 8;
      float t = 0.f;
#pragma unroll
      for (int c = 0; c < 8; c++) {
        const float kv = (float)SMB[X1Ho + rr * 72 + cs + c] + (float)SMB[X1Lo + rr * 72 + cs + c];
        t += kv * F[F_B + 192 + cs + c];
      }
      t += __shfl_xor(t, 1);
      t += __shfl_xor(t, 2);
      t += __shfl_xor(t, 4);
      if ((tid & 7) == 0) F[F_C0 + rr] = t;
    }
  }
  __syncthreads();

  // ---- P7: qo-score -> eh ----
  {
    const int idx = tid >> 1, g2 = tid & 1;
    const int i = idx >> 4, j = idx & 15;
    const float wij = F[F_WSIG + i * 16 + j];
    float z[8];
#pragma unroll
    for (int c = 0; c < 8; c++)
      z[c] = F[F_PI + j * 8 + c] + wij * (F[F_ACT + j * 8 + c] - F[F_PI + j * 8 + c]);
    float sc = 0.f;
#pragma unroll
    for (int gg = 2 * g2; gg <= 2 * g2 + 1; gg++) {
#pragma unroll
      for (int t = 0; t < 16; t++) {
        const float4 wa = *(const float4*)(F + F_WZQ + t * 32 + gg * 8);
        const float4 wb = *(const float4*)(F + F_WZQ + t * 32 + gg * 8 + 4);
        float hv = F[F_S3G + t * 68 + j * 4 + gg]
          + wa.x * z[0] + wa.y * z[1] + wa.z * z[2] + wa.w * z[3]
          + wb.x * z[4] + wb.y * z[5] + wb.z * z[6] + wb.w * z[7];
        hv = lrelu(hv);
        sc += F[F_S2 + i * 68 + gg * 16 + t] * hv;
      }
    }
    sc += __shfl_xor(sc, 1);
    if (g2 == 0) {
      float yv = (sc + F[F_C0 + i]) * 0.125f;
      yv = fminf(fmaxf(yv, -5.f), 5.f);
      SMB[EHO + idx] = (f16)__expf(yv);
    }
  }
  __syncthreads();

  // ---- P8: softmax -> wo ; stage fv weights (over dead ko1/ko2 slots) ----
  if (tid < 256) {
    const int i = tid >> 4, j = tid & 15;
    float ev[16]; float mx = -1e30f;
#pragma unroll
    for (int jj = 0; jj < 16; jj++) { ev[jj] = (float)SMB[EHO + i * 16 + jj]; mx = fmaxf(mx, ev[jj]); }
    float den = 0.f;
#pragma unroll
    for (int jj = 0; jj < 16; jj++) den += __expf(ev[jj] - mx);
    F[F_WO + tid] = __expf(ev[j] - mx) / den;
  }
#pragma unroll
  for (int qq = 0; qq < 4; qq++) {
    const int e0 = tid * 16 + qq * 4;
    h2* d = (h2*)&SMB[FV1H + (e0 >> 7) * 136 + (e0 & 127)];
    d[0] = h2{(f16)rfv[qq].x, (f16)rfv[qq].y};
    d[1] = h2{(f16)rfv[qq].z, (f16)rfv[qq].w};
  }
  SMB[FV2PW + tid] = (f16)rfv2;
  {
    float* BF2w = (float*)(SMB + BACKB2);
    if (tid < 64) BF2w[tid] = rb3;
    if (tid < 8) BF2w[64 + tid] = rb4;
  }
  __syncthreads();

  // ---- P9: final — mixed + fv1 + fv2 + out0 + out2 (all 8 waves) ----
  {
    const float* BF2 = (const float*)(SMB + BACKB2);
    const int i_ = ihalf * 8 + w;
    f16* Sl = (w < 4) ? (SMB + SLA + w * 1536) : (SMB + SLB + (w - 4) * 1536);
    v8h am;
#pragma unroll
    for (int e = 0; e < 8; e++) {
      const int j2 = quad * 8 + e;
      float v;
      if (j2 < 16) v = F[F_WO + m * 16 + j2] * 0.0625f;
      else v = (j2 - 16 == m) ? F[F_WO + m * 17] * 0.0625f : 0.f;
      am[e] = (f16)v;
    }
    {
      v4f macc[4];
#pragma unroll
      for (int nt = 0; nt < 4; nt++) {
        const int oo = nt * 16 + m;
        v8h bf;
        if (quad < 2) {
          bf = *(const v8h*)(Sl + oo * 24 + quad * 8);
        } else {
          const v8h apv = *(const v8h*)(&SMB[APTO + oo * 24 + (quad - 2) * 8]);
          const v8h aov = *(const v8h*)(Sl + oo * 24 + (quad - 2) * 8);
          bf = apv - aov;
        }
        v4f z4 = {0.f, 0.f, 0.f, 0.f};
        macc[nt] = __builtin_amdgcn_mfma_f32_16x16x32_f16(am, bf, z4, 0, 0, 0);
      }
#pragma unroll
      for (int nt = 0; nt < 4; nt++)
#pragma unroll
        for (int reg = 0; reg < 4; reg++)
          Sl[(quad * 4 + reg) * 72 + nt * 16 + m] = (f16)macc[nt][reg];
    }
    {
      const v8h f0 = *(const v8h*)(&SMB[AOSRC + m * 72 + quad * 8]);
      const v8h f1 = *(const v8h*)(&SMB[AOSRC + m * 72 + 32 + quad * 8]);
      const v8h f2 = *(const v8h*)(Sl + m * 72 + quad * 8);
      const v8h f3 = *(const v8h*)(Sl + m * 72 + 32 + quad * 8);
#pragma unroll
      for (int nt = 0; nt < 4; nt++) {
        const float bv = BF2[nt * 16 + m];
        v4f acc = {bv, bv, bv, bv};
        acc = __builtin_amdgcn_mfma_f32_16x16x32_f16(f0, bfrag(SMB + FV1H, 136, nt, 0, lane), acc, 0, 0, 0);
        acc = __builtin_amdgcn_mfma_f32_16x16x32_f16(f1, bfrag(SMB + FV1H, 136, nt, 1, lane), acc, 0, 0, 0);
        acc = __builtin_amdgcn_mfma_f32_16x16x32_f16(f2, bfrag(SMB + FV1H, 136, nt, 2, lane), acc, 0, 0, 0);
        acc = __builtin_amdgcn_mfma_f32_16x16x32_f16(f3, bfrag(SMB + FV1H, 136, nt, 3, lane), acc, 0, 0, 0);
#pragma unroll
        for (int reg = 0; reg < 4; reg++)
          Sl[(quad * 4 + reg) * 72 + nt * 16 + m] = (f16)lrelu(acc[reg]);
      }
    }
    {
      const int g2 = quad;
      float y0 = BF2[64 + 2 * g2], y1 = BF2[64 + 2 * g2 + 1];
#pragma unroll
      for (int o2 = 0; o2 < 32; o2++) {
        const h2 hh = *(const h2*)(Sl + m * 72 + 2 * o2);
        const h2 w0v = *(const h2*)(&SMB[FV2PW + (2 * g2) * 64 + 2 * o2]);
        const h2 w1v = *(const h2*)(&SMB[FV2PW + (2 * g2 + 1) * 64 + 2 * o2]);
        y0 = fdot2f(w0v, hh, y0);
        y1 = fdot2f(w1v, hh, y1);
      }
      *(float2*)(p.out0 + ((size_t)b * 256 + i_ * 16 + m) * 8 + 2 * g2) = make_float2(y0, y1);
    }
    {
      const float4 wv4 = *(const float4*)(F + F_WO + m * 16 + quad * 4);
      *(float4*)(p.out2 + ((size_t)b * 256 + i_ * 16 + m) * 16 + quad * 4) = wv4;
    }
  }
}

extern "C" void kernel_launch(void* const* d_in, const int* in_sizes, int n_in,
                              void* d_out, int out_size, void* d_ws, size_t ws_size,
                              hipStream_t stream) {
  P p;
  p.obs = (const float*)d_in[0];
  p.pol = (const float*)d_in[1];
  p.act = (const float*)d_in[2];
  p.kw1w = (const float*)d_in[3];  p.kw1b = (const float*)d_in[4];
  p.kw2w = (const float*)d_in[5];  p.kw2b = (const float*)d_in[6];
  p.qw1w = (const float*)d_in[7];  p.qw1b = (const float*)d_in[8];
  p.qw2w = (const float*)d_in[9];  p.qw2b = (const float*)d_in[10];
  p.ko1w = (const float*)d_in[11]; p.ko1b = (const float*)d_in[12];
  p.ko2w = (const float*)d_in[13]; p.ko2b = (const float*)d_in[14];
  p.qo1w = (const float*)d_in[15]; p.qo1b = (const float*)d_in[16];
  p.qo2w = (const float*)d_in[17]; p.qo2b = (const float*)d_in[18];
  p.av1w = (const float*)d_in[19]; p.av1b = (const float*)d_in[20];
  p.av2w = (const float*)d_in[21]; p.av2b = (const float*)d_in[22];
  p.fv1w = (const float*)d_in[23]; p.fv1b = (const float*)d_in[24];
  p.fv2w = (const float*)d_in[25]; p.fv2b = (const float*)d_in[26];

  const int Bn = in_sizes[0] / (A_ * DOBS_);   // 128
  p.out0 = (float*)d_out;
  p.out1 = p.out0 + (size_t)Bn * A_ * A_ * NA_;
  p.out2 = p.out1 + (size_t)Bn * A_ * A_;

  const size_t lds_bytes = (size_t)LDS_F16 * sizeof(f16);   // 159552
  (void)hipFuncSetAttribute(reinterpret_cast<const void*>(critic_fused),
                            hipFuncAttributeMaxDynamicSharedMemorySize, (int)lds_bytes);
  hipLaunchKernelGGL(critic_fused, dim3(2 * Bn), dim3(512), lds_bytes, stream, p);
}